// Round 5
// baseline (4125.265 us; speedup 1.0000x reference)
//
#include <hip/hip_runtime.h>

typedef unsigned short u16;
typedef __attribute__((ext_vector_type(8))) short bf8;   // 8 x bf16 (4 VGPRs) MFMA operand
typedef __attribute__((ext_vector_type(4))) float f4;    // MFMA accumulator

#define DEVI static __device__ __forceinline__

constexpr int Bb = 128, Tt = 512, Dd = 128, Hh = 256, G4 = 1024;
constexpr int CH  = 64;        // timesteps per chunk
constexpr int NCH = Tt / CH;   // 8 chunks
constexpr int MCH = CH * Bb;   // 8192 GEMM rows per chunk

DEVI u16 f2bf(float f) {
  union { float f; unsigned u; } v; v.f = f;
  unsigned r = v.u + 0x7FFFu + ((v.u >> 16) & 1u);  // RNE
  return (u16)(r >> 16);
}
DEVI float bf2f(u16 b) { union { unsigned u; float f; } v; v.u = ((unsigned)b) << 16; return v.f; }
DEVI float sigm(float x) { return 1.f / (1.f + __expf(-x)); }
DEVI float tanh_f(float x) {
  float e = __expf(-2.f * fabsf(x));
  float t = (1.f - e) / (1.f + e);
  return copysignf(t, x);
}
DEVI f4 mfma16(bf8 a, bf8 b, f4 c) {
  return __builtin_amdgcn_mfma_f32_16x16x32_bf16(a, b, c, 0, 0, 0);
}

// ---------- prep kernels ----------

__global__ void k_prep_x(const float* __restrict__ X, u16* __restrict__ Xhi, u16* __restrict__ Xlo) {
  size_t idx = (size_t)blockIdx.x * 256 + threadIdx.x;      // (b*T+t)*D + d
  int d = (int)(idx % Dd);
  size_t bt = idx / Dd;
  int b = (int)(bt / Tt), t = (int)(bt % Tt);
  float x = X[idx];
  u16 hi = f2bf(x);
  u16 lo = f2bf(x - bf2f(hi));
  size_t o = ((size_t)t * Bb + b) * Dd + d;
  Xhi[o] = hi; Xlo[o] = lo;
}

__global__ void k_split(const float* __restrict__ W, u16* __restrict__ hi_, u16* __restrict__ lo_) {
  size_t idx = (size_t)blockIdx.x * 256 + threadIdx.x;
  float v = W[idx];
  u16 hi = f2bf(v);
  hi_[idx] = hi;
  lo_[idx] = f2bf(v - bf2f(hi));
}

// Whh[4H,H] -> fragment-linear bf16 W2: offset jtg*4096 + kt*512 + lane*8 + i
// holds B[k][col], gate col_global = (jtg>>4)*256 + (jtg&15)*16 + (lane&15), k = kt*32+(lane>>4)*8+i
__global__ void k_prep_whh(const float* __restrict__ Whh, u16* __restrict__ W2) {
  int idx = blockIdx.x * 256 + threadIdx.x;           // 4H*H = 262144
  int i = idx & 7, lane = (idx >> 3) & 63, kt = (idx >> 9) & 7, jtg = idx >> 12;
  int jp = (jtg << 4) + (lane & 15);
  int k  = ((lane >> 4) << 3) + i + (kt << 5);
  W2[idx] = f2bf(Whh[(size_t)jp * Hh + k]);
}

__global__ void k_bias(const float* __restrict__ a, const float* __restrict__ b, float* __restrict__ o) {
  int i = blockIdx.x * 256 + threadIdx.x;
  if (i < G4) o[i] = a[i] + b[i];
}

__global__ void k_zero(int* __restrict__ p, int n) {
  int i = blockIdx.x * 256 + threadIdx.x;
  if (i < n) p[i] = 0;
}

// ---------- input GEMM: gates = A[M,K] @ W[1024,K]^T + bias, written in XGF layout ----------
// XGF f4 index: ((((t*8 + g)*8 + s)*2 + w)*4 + q)*64 + lane
//   t = chunk-local timestep, b = g*16 + (lane>>4)*4 + r, col = q*256 + s*32 + w*16 + (lane&15)
template <int K, bool ALO>
__global__ void __launch_bounds__(256) k_gemm(
    const u16* __restrict__ Ahi, const u16* __restrict__ Alo,
    const u16* __restrict__ Whi, const u16* __restrict__ Wlo,
    const float* __restrict__ bias, float* __restrict__ Cout) {
  __shared__ u16 AsH[128][32];
  __shared__ u16 AsL[128][32];
  const int tid = threadIdx.x, l = tid & 63;
  const int w = tid >> 6, wm = w >> 1, wn = w & 1;
  const int lrow = l & 15, lk = (l >> 4) << 3;
  const size_t m0 = (size_t)blockIdx.x * 128;
  const int n0 = blockIdx.y * 128;

  f4 acc[4][4];
  size_t colK[4];
#pragma unroll
  for (int ni = 0; ni < 4; ++ni) {
    int col = n0 + wn * 64 + ni * 16 + lrow;
    float bv = bias[col];
    colK[ni] = (size_t)col * K + lk;
#pragma unroll
    for (int mi = 0; mi < 4; ++mi) {
      acc[mi][ni][0] = bv; acc[mi][ni][1] = bv; acc[mi][ni][2] = bv; acc[mi][ni][3] = bv;
    }
  }

  for (int kk = 0; kk < K; kk += 32) {
    __syncthreads();
#pragma unroll
    for (int s = 0; s < 2; ++s) {
      int slot = s * 256 + tid;
      int r = slot >> 2, kg = (slot & 3) << 3;
      *(bf8*)&AsH[r][kg] = *(const bf8*)&Ahi[(m0 + r) * K + kk + kg];
      if constexpr (ALO) *(bf8*)&AsL[r][kg] = *(const bf8*)&Alo[(m0 + r) * K + kk + kg];
    }
    __syncthreads();

    bf8 bh[4], bl[4];
#pragma unroll
    for (int ni = 0; ni < 4; ++ni) {
      bh[ni] = *(const bf8*)&Whi[colK[ni] + kk];
      bl[ni] = *(const bf8*)&Wlo[colK[ni] + kk];
    }
    bf8 ah[4], al[4];
#pragma unroll
    for (int mi = 0; mi < 4; ++mi) {
      ah[mi] = *(const bf8*)&AsH[wm * 64 + mi * 16 + lrow][lk];
      if constexpr (ALO) al[mi] = *(const bf8*)&AsL[wm * 64 + mi * 16 + lrow][lk];
    }
#pragma unroll
    for (int mi = 0; mi < 4; ++mi)
#pragma unroll
      for (int ni = 0; ni < 4; ++ni) {
        acc[mi][ni] = mfma16(ah[mi], bh[ni], acc[mi][ni]);
        acc[mi][ni] = mfma16(ah[mi], bl[ni], acc[mi][ni]);
        if constexpr (ALO) acc[mi][ni] = mfma16(al[mi], bh[ni], acc[mi][ni]);
      }
  }

  // epilogue: XGF layout, one fully-coalesced f4 store per (mi,ni)
  f4* C4 = (f4*)Cout;
  const int by = blockIdx.y;
#pragma unroll
  for (int mi = 0; mi < 4; ++mi) {
    int gg = wm * 4 + mi;                       // batch-group
#pragma unroll
    for (int ni = 0; ni < 4; ++ni) {
      int colb = by * 128 + wn * 64 + ni * 16;  // col base (lrow = 0)
      int q  = colb >> 8;
      int ss = (colb >> 5) & 7;
      int wt = (colb >> 4) & 1;
      C4[(((((size_t)blockIdx.x * 8 + gg) * 8 + ss) * 2 + wt) * 4 + q) * 64 + l] = acc[mi][ni];
    }
  }
}

// ---------- recurrence: 64 blocks (8 groups x 8 j-slices) x 128 thr (2 waves) ----------
// Block (g,s): batches [16g,16g+16), hidden j in [32s,32s+32); wave w owns jt = 2s+w.
// Whh slice (64 KB) LDS-resident. Cross-block h exchange per step via hseq + padded
// per-(step,group) counters: release-fence + relaxed add, relaxed poll, one acquire fence.
__global__ void __launch_bounds__(128) k_recur(
    const float* __restrict__ xg,   // chunk in XGF layout (biases folded)
    const u16* __restrict__ W2,     // fragment-linear Whh bf16
    u16* __restrict__ hseq,         // [T][128][256] bf16 (also the exchange medium)
    float* __restrict__ cst,        // [128][256] fp32 carry
    int* __restrict__ cnt,          // [T][8] step counters, 128B-padded (zeroed each launch)
    int t0) {
  __shared__ u16 wlds[32768];       // 64 KB: [jl][kt][512], jl = q*2 + w
  __shared__ u16 hb[2][4096];       // [16][256] bf16, granule-XOR swizzled, dbuf
  const int tid = threadIdx.x, l = tid & 63, w = tid >> 6;   // w in {0,1}
  const int lrow = l & 15, lg = l >> 4;
  const int g = blockIdx.x & 7, s = blockIdx.x >> 3;
  const int b_base = g << 4;
  const int jmy = (s << 5) + (w << 4) + lrow;   // my hidden column

  // stage W slice: granule f -> jl = f>>9, kt = (f>>6)&7, e = f&63; jtg = (jl>>1)*16 + 2s + (jl&1)
  for (int u = 0; u < 32; ++u) {
    int f = u * 128 + tid;
    int jl = f >> 9, kt = (f >> 6) & 7, e = f & 63;
    int jtg = ((jl >> 1) << 4) + (s << 1) + (jl & 1);
    *(bf8*)&wlds[f << 3] = *(const bf8*)&W2[((size_t)jtg << 12) + (kt << 9) + (e << 3)];
  }

  float cc4[4];                     // c for b = lg*4+rr, j = jmy
  if (t0 == 0) {
    cc4[0] = cc4[1] = cc4[2] = cc4[3] = 0.f;
    for (int i = tid; i < 4096; i += 128) hb[0][i] = 0;
  } else {
#pragma unroll
    for (int rr = 0; rr < 4; ++rr)
      cc4[rr] = cst[(size_t)(b_base + (lg << 2) + rr) * Hh + jmy];
    const u16* hp = hseq + ((size_t)(t0 - 1) * Bb + b_base) * Hh;
    int b = tid >> 3, gr = tid & 7;
#pragma unroll
    for (int u = 0; u < 4; ++u) {
      int g8 = (gr << 2) + u;
      *(bf8*)&hb[0][(b << 8) + ((g8 ^ b) << 3)] = *(const bf8*)&hp[(size_t)b * Hh + (g8 << 3)];
    }
  }
  __syncthreads();

  const f4* xb = (const f4*)xg + ((((size_t)g * 8 + s) * 2 + w) * 4) * 64 + l;
  f4 xgn[4];
#pragma unroll
  for (int q = 0; q < 4; ++q) xgn[q] = xb[q << 6];

  int cur = 0;
  for (int t = 0; t < CH; ++t) {
    bf8 af[8];
#pragma unroll
    for (int kt = 0; kt < 8; ++kt)
      af[kt] = *(const bf8*)&hb[cur][(lrow << 8) + ((((kt << 2) + lg) ^ lrow) << 3)];

    f4 acc[4];
#pragma unroll
    for (int q = 0; q < 4; ++q) acc[q] = xgn[q];

    // kt-major, B double-buffered at kt granularity; 4 independent acc chains
    bf8 b0[4], b1[4];
#pragma unroll
    for (int q = 0; q < 4; ++q)
      b0[q] = *(const bf8*)&wlds[(((((q << 1) | w) << 3) | 0) << 9) + (l << 3)];
#pragma unroll
    for (int kt = 0; kt < 8; ++kt) {
      bf8* bc = (kt & 1) ? b1 : b0;
      bf8* bn = (kt & 1) ? b0 : b1;
      if (kt < 7) {
#pragma unroll
        for (int q = 0; q < 4; ++q)
          bn[q] = *(const bf8*)&wlds[(((((q << 1) | w) << 3) | (kt + 1)) << 9) + (l << 3)];
      }
#pragma unroll
      for (int q = 0; q < 4; ++q) acc[q] = mfma16(af[kt], bc[q], acc[q]);
    }

    if (t + 1 < CH) {
#pragma unroll
      for (int q = 0; q < 4; ++q) xgn[q] = xb[(size_t)(t + 1) * 32768 + (q << 6)];
    }

    u16 hv[4];
#pragma unroll
    for (int rr = 0; rr < 4; ++rr) {
      float gi = sigm(acc[0][rr]);
      float gf = sigm(acc[1][rr]);
      float gg = tanh_f(acc[2][rr]);
      float go = sigm(acc[3][rr]);
      float c2 = gf * cc4[rr] + gi * gg;
      cc4[rr] = c2;
      hv[rr] = f2bf(go * tanh_f(c2));
    }

    const int tg = t0 + t;
    u16* hrow = hseq + ((size_t)tg * Bb + b_base) * Hh;
#pragma unroll
    for (int rr = 0; rr < 4; ++rr)
      hrow[(size_t)((lg << 2) + rr) * Hh + jmy] = hv[rr];

    if (t + 1 < CH) {
      __syncthreads();              // block-wide vmcnt(0): h stores complete in local L2
      if (tid == 0) {
        int* flag = &cnt[((tg << 3) + g) << 5];      // 128B-padded counter
        __builtin_amdgcn_fence(__ATOMIC_RELEASE, "agent");   // one wbl2: h -> coherence pt
        __hip_atomic_fetch_add(flag, 1, __ATOMIC_RELAXED, __HIP_MEMORY_SCOPE_AGENT);
        while (__hip_atomic_load(flag, __ATOMIC_RELAXED, __HIP_MEMORY_SCOPE_AGENT) < 8)
          __builtin_amdgcn_s_sleep(1);
        __builtin_amdgcn_fence(__ATOMIC_ACQUIRE, "agent");   // one inv before h reload
      }
      __syncthreads();
      int nxt = cur ^ 1;
      const u16* hp = hseq + ((size_t)tg * Bb + b_base) * Hh;
      int b = tid >> 3, gr = tid & 7;
#pragma unroll
      for (int u = 0; u < 4; ++u) {
        int g8 = (gr << 2) + u;
        *(bf8*)&hb[nxt][(b << 8) + ((g8 ^ b) << 3)] = *(const bf8*)&hp[(size_t)b * Hh + (g8 << 3)];
      }
      __syncthreads();
      cur = nxt;
    }
  }

#pragma unroll
  for (int rr = 0; rr < 4; ++rr)
    cst[(size_t)(b_base + (lg << 2) + rr) * Hh + jmy] = cc4[rr];
}

// ---------- final FC ----------
__global__ void k_fc(const u16* __restrict__ h2l, const float* __restrict__ Wfc,
                     const float* __restrict__ bfc, float* __restrict__ out) {
  int b = threadIdx.x;
  if (b < Bb) {
    float s = bfc[0];
    for (int j = 0; j < Hh; ++j) s += bf2f(h2l[(size_t)b * Hh + j]) * Wfc[j];
    out[b] = s;
  }
}

// ---------- driver ----------
extern "C" void kernel_launch(void* const* d_in, const int* in_sizes, int n_in,
                              void* d_out, int out_size, void* d_ws, size_t ws_size,
                              hipStream_t stream) {
  const float* X    = (const float*)d_in[0];
  const float* Wih0 = (const float*)d_in[1];
  const float* Whh0 = (const float*)d_in[2];
  const float* bih0 = (const float*)d_in[3];
  const float* bhh0 = (const float*)d_in[4];
  const float* Wih1 = (const float*)d_in[5];
  const float* Whh1 = (const float*)d_in[6];
  const float* bih1 = (const float*)d_in[7];
  const float* bhh1 = (const float*)d_in[8];
  const float* Wfc  = (const float*)d_in[9];
  const float* bfc  = (const float*)d_in[10];

  char* base = (char*)d_ws;
  size_t off = 0;
  auto alloc = [&](size_t bytes) -> char* {
    char* p = base + off;
    off = (off + bytes + 255) & ~(size_t)255;
    return p;
  };

  u16* Xhi = (u16*)alloc((size_t)Bb * Tt * Dd * 2);
  u16* Xlo = (u16*)alloc((size_t)Bb * Tt * Dd * 2);
  u16* W0h = (u16*)alloc((size_t)G4 * Dd * 2);
  u16* W0l = (u16*)alloc((size_t)G4 * Dd * 2);
  u16* W1h = (u16*)alloc((size_t)G4 * Hh * 2);
  u16* W1l = (u16*)alloc((size_t)G4 * Hh * 2);
  u16* W2a = (u16*)alloc((size_t)G4 * Hh * 2);
  u16* W2b = (u16*)alloc((size_t)G4 * Hh * 2);
  float* b0 = (float*)alloc(G4 * 4);
  float* b1 = (float*)alloc(G4 * 4);
  float* xgb = (float*)alloc((size_t)MCH * G4 * 4);     // 33.5 MB chunk buffer (XGF layout)
  u16* h1 = (u16*)alloc((size_t)Tt * Bb * Hh * 2);
  u16* h2 = (u16*)alloc((size_t)Tt * Bb * Hh * 2);
  float* cst = (float*)alloc((size_t)Bb * Hh * 4);
  int* cnt = (int*)alloc((size_t)2 * Tt * 8 * 32 * 4);  // 128B-padded [layer][T][8] counters

  k_zero<<<(2 * Tt * 8 * 32 + 255) / 256, 256, 0, stream>>>(cnt, 2 * Tt * 8 * 32);
  k_prep_x<<<(Bb * Tt * Dd) / 256, 256, 0, stream>>>(X, Xhi, Xlo);
  k_split<<<(G4 * Dd) / 256, 256, 0, stream>>>(Wih0, W0h, W0l);
  k_split<<<(G4 * Hh) / 256, 256, 0, stream>>>(Wih1, W1h, W1l);
  k_prep_whh<<<(G4 * Hh) / 256, 256, 0, stream>>>(Whh0, W2a);
  k_prep_whh<<<(G4 * Hh) / 256, 256, 0, stream>>>(Whh1, W2b);
  k_bias<<<4, 256, 0, stream>>>(bih0, bhh0, b0);
  k_bias<<<4, 256, 0, stream>>>(bih1, bhh1, b1);

  for (int c = 0; c < NCH; ++c) {
    k_gemm<Dd, true><<<dim3(64, 8), 256, 0, stream>>>(
        Xhi + (size_t)c * MCH * Dd, Xlo + (size_t)c * MCH * Dd, W0h, W0l, b0, xgb);
    k_recur<<<64, 128, 0, stream>>>(xgb, W2a, h1, cst, cnt, c * CH);
  }
  for (int c = 0; c < NCH; ++c) {
    k_gemm<Hh, false><<<dim3(64, 8), 256, 0, stream>>>(
        h1 + (size_t)c * MCH * Hh, nullptr, W1h, W1l, b1, xgb);
    k_recur<<<64, 128, 0, stream>>>(xgb, W2b, h2, cst, cnt + Tt * 8 * 32, c * CH);
  }
  k_fc<<<1, 128, 0, stream>>>(h2 + (size_t)(Tt - 1) * Bb * Hh, Wfc, bfc, (float*)d_out);

  (void)in_sizes; (void)n_in; (void)out_size; (void)ws_size;
}

// Round 6
// 3657.829 us; speedup vs baseline: 1.1278x; 1.1278x over previous
//
#include <hip/hip_runtime.h>

typedef unsigned short u16;
typedef __attribute__((ext_vector_type(8))) short bf8;   // 8 x bf16 (4 VGPRs) MFMA operand
typedef __attribute__((ext_vector_type(4))) float f4;    // MFMA accumulator

#define DEVI static __device__ __forceinline__

constexpr int Bb = 128, Tt = 512, Dd = 128, Hh = 256, G4 = 1024;
constexpr int CH  = 64;        // timesteps per chunk
constexpr int NCH = Tt / CH;   // 8 chunks
constexpr int MCH = CH * Bb;   // 8192 GEMM rows per chunk

DEVI u16 f2bf(float f) {
  union { float f; unsigned u; } v; v.f = f;
  unsigned r = v.u + 0x7FFFu + ((v.u >> 16) & 1u);  // RNE
  return (u16)(r >> 16);
}
DEVI float bf2f(u16 b) { union { unsigned u; float f; } v; v.u = ((unsigned)b) << 16; return v.f; }
DEVI float sigm(float x) { return 1.f / (1.f + __expf(-x)); }
DEVI float tanh_f(float x) {
  float e = __expf(-2.f * fabsf(x));
  float t = (1.f - e) / (1.f + e);
  return copysignf(t, x);
}
DEVI f4 mfma16(bf8 a, bf8 b, f4 c) {
  return __builtin_amdgcn_mfma_f32_16x16x32_bf16(a, b, c, 0, 0, 0);
}
// device-coherent (MALL-direct, L1/L2-bypass) 16B ops
DEVI bf8 ld_coh16(const u16* p) {
  bf8 r;
  asm volatile("global_load_dwordx4 %0, %1, off sc0 sc1" : "=&v"(r) : "v"(p) : "memory");
  return r;
}
DEVI void st_coh16(u16* p, bf8 v) {
  asm volatile("global_store_dwordx4 %0, %1, off sc0 sc1" :: "v"(p), "v"(v) : "memory");
}

// ---------- prep kernels ----------

__global__ void k_prep_x(const float* __restrict__ X, u16* __restrict__ Xhi, u16* __restrict__ Xlo) {
  size_t idx = (size_t)blockIdx.x * 256 + threadIdx.x;      // (b*T+t)*D + d
  int d = (int)(idx % Dd);
  size_t bt = idx / Dd;
  int b = (int)(bt / Tt), t = (int)(bt % Tt);
  float x = X[idx];
  u16 hi = f2bf(x);
  u16 lo = f2bf(x - bf2f(hi));
  size_t o = ((size_t)t * Bb + b) * Dd + d;
  Xhi[o] = hi; Xlo[o] = lo;
}

__global__ void k_split(const float* __restrict__ W, u16* __restrict__ hi_, u16* __restrict__ lo_) {
  size_t idx = (size_t)blockIdx.x * 256 + threadIdx.x;
  float v = W[idx];
  u16 hi = f2bf(v);
  hi_[idx] = hi;
  lo_[idx] = f2bf(v - bf2f(hi));
}

// Whh[4H,H] -> fragment-linear bf16 W2: offset jtg*4096 + kt*512 + lane*8 + i
// holds B[k][col], gate col_global = (jtg>>4)*256 + (jtg&15)*16 + (lane&15), k = kt*32+(lane>>4)*8+i
__global__ void k_prep_whh(const float* __restrict__ Whh, u16* __restrict__ W2) {
  int idx = blockIdx.x * 256 + threadIdx.x;           // 4H*H = 262144
  int i = idx & 7, lane = (idx >> 3) & 63, kt = (idx >> 9) & 7, jtg = idx >> 12;
  int jp = (jtg << 4) + (lane & 15);
  int k  = ((lane >> 4) << 3) + i + (kt << 5);
  W2[idx] = f2bf(Whh[(size_t)jp * Hh + k]);
}

__global__ void k_bias(const float* __restrict__ a, const float* __restrict__ b, float* __restrict__ o) {
  int i = blockIdx.x * 256 + threadIdx.x;
  if (i < G4) o[i] = a[i] + b[i];
}

__global__ void k_zero(int* __restrict__ p, int n) {
  int i = blockIdx.x * 256 + threadIdx.x;
  if (i < n) p[i] = 0;
}

__global__ void k_zrow(u16* __restrict__ a, u16* __restrict__ b) {
  int i = blockIdx.x * 256 + threadIdx.x;
  if (i < Bb * Hh) { a[i] = 0; b[i] = 0; }
}

// ---------- input GEMM: gates = A[M,K] @ W[1024,K]^T + bias, written in XGF layout ----------
// XGF f4 index: ((((t*8 + g)*8 + s)*2 + w)*4 + q)*64 + lane
//   t = chunk-local timestep, b = g*16 + (lane>>4)*4 + r, col = q*256 + s*32 + w*16 + (lane&15)
template <int K, bool ALO>
__global__ void __launch_bounds__(256) k_gemm(
    const u16* __restrict__ Ahi, const u16* __restrict__ Alo,
    const u16* __restrict__ Whi, const u16* __restrict__ Wlo,
    const float* __restrict__ bias, float* __restrict__ Cout) {
  __shared__ u16 AsH[128][32];
  __shared__ u16 AsL[128][32];
  const int tid = threadIdx.x, l = tid & 63;
  const int w = tid >> 6, wm = w >> 1, wn = w & 1;
  const int lrow = l & 15, lk = (l >> 4) << 3;
  const size_t m0 = (size_t)blockIdx.x * 128;
  const int n0 = blockIdx.y * 128;

  f4 acc[4][4];
  size_t colK[4];
#pragma unroll
  for (int ni = 0; ni < 4; ++ni) {
    int col = n0 + wn * 64 + ni * 16 + lrow;
    float bv = bias[col];
    colK[ni] = (size_t)col * K + lk;
#pragma unroll
    for (int mi = 0; mi < 4; ++mi) {
      acc[mi][ni][0] = bv; acc[mi][ni][1] = bv; acc[mi][ni][2] = bv; acc[mi][ni][3] = bv;
    }
  }

  for (int kk = 0; kk < K; kk += 32) {
    __syncthreads();
#pragma unroll
    for (int s = 0; s < 2; ++s) {
      int slot = s * 256 + tid;
      int r = slot >> 2, kg = (slot & 3) << 3;
      *(bf8*)&AsH[r][kg] = *(const bf8*)&Ahi[(m0 + r) * K + kk + kg];
      if constexpr (ALO) *(bf8*)&AsL[r][kg] = *(const bf8*)&Alo[(m0 + r) * K + kk + kg];
    }
    __syncthreads();

    bf8 bh[4], bl[4];
#pragma unroll
    for (int ni = 0; ni < 4; ++ni) {
      bh[ni] = *(const bf8*)&Whi[colK[ni] + kk];
      bl[ni] = *(const bf8*)&Wlo[colK[ni] + kk];
    }
    bf8 ah[4], al[4];
#pragma unroll
    for (int mi = 0; mi < 4; ++mi) {
      ah[mi] = *(const bf8*)&AsH[wm * 64 + mi * 16 + lrow][lk];
      if constexpr (ALO) al[mi] = *(const bf8*)&AsL[wm * 64 + mi * 16 + lrow][lk];
    }
#pragma unroll
    for (int mi = 0; mi < 4; ++mi)
#pragma unroll
      for (int ni = 0; ni < 4; ++ni) {
        acc[mi][ni] = mfma16(ah[mi], bh[ni], acc[mi][ni]);
        acc[mi][ni] = mfma16(ah[mi], bl[ni], acc[mi][ni]);
        if constexpr (ALO) acc[mi][ni] = mfma16(al[mi], bh[ni], acc[mi][ni]);
      }
  }

  // epilogue: XGF layout, one fully-coalesced f4 store per (mi,ni)
  f4* C4 = (f4*)Cout;
  const int by = blockIdx.y;
#pragma unroll
  for (int mi = 0; mi < 4; ++mi) {
    int gg = wm * 4 + mi;                       // batch-group
#pragma unroll
    for (int ni = 0; ni < 4; ++ni) {
      int colb = by * 128 + wn * 64 + ni * 16;  // col base (lrow = 0)
      int q  = colb >> 8;
      int ss = (colb >> 5) & 7;
      int wt = (colb >> 4) & 1;
      C4[(((((size_t)blockIdx.x * 8 + gg) * 8 + ss) * 2 + wt) * 4 + q) * 64 + l] = acc[mi][ni];
    }
  }
}

// ---------- recurrence: 64 blocks (8 groups g x 8 j-slices s) x 128 thr (2 waves) ----------
// Block (g,s): batches [16g,16g+16), hidden j in [32s,32s+32); wave w owns jt = 2s+w.
// Whh slice (64 KB) LDS-resident. h exchanged via sc0|sc1 (MALL-direct) stores/loads:
// no L2 state -> no wbl2/inv cost, no reload phase; af fragments loaded straight from
// global per kt with counted vmcnt(7-kt) waits so MFMA overlaps load latency.
// hz is hseq shifted by one row (row 0 = zeros): step t reads row t0+t, writes t0+t+1.
__global__ void __launch_bounds__(128) k_recur(
    const float* __restrict__ xg,   // chunk in XGF layout (biases folded)
    const u16* __restrict__ W2,     // fragment-linear Whh bf16
    u16* __restrict__ hz,           // [T+1][128][256] bf16 (exchange medium, sc1 ops)
    float* __restrict__ cst,        // [128][256] fp32 carry
    int* __restrict__ cnt,          // [T][8] step counters, 128B-padded (zeroed each launch)
    int t0) {
  __shared__ u16 wlds[32768];       // 64 KB: [jl][kt][512], jl = q*2 + w
  __shared__ u16 sbuf[512];         // 1 KB own-slice staging: [16 b][32 j]
  const int tid = threadIdx.x, l = tid & 63, w = tid >> 6;   // w in {0,1}
  const int lrow = l & 15, lg = l >> 4;
  const int g = blockIdx.x & 7, s = blockIdx.x >> 3;
  const int b_base = g << 4;
  const int jmy = (s << 5) + (w << 4) + lrow;   // my hidden column

  // stage W slice: granule f -> jl = f>>9, kt = (f>>6)&7, e = f&63; jtg = (jl>>1)*16 + 2s + (jl&1)
  for (int u = 0; u < 32; ++u) {
    int f = u * 128 + tid;
    int jl = f >> 9, kt = (f >> 6) & 7, e = f & 63;
    int jtg = ((jl >> 1) << 4) + (s << 1) + (jl & 1);
    *(bf8*)&wlds[f << 3] = *(const bf8*)&W2[((size_t)jtg << 12) + (kt << 9) + (e << 3)];
  }

  float cc4[4];                     // c for b = lg*4+rr, j = jmy
  if (t0 == 0) {
    cc4[0] = cc4[1] = cc4[2] = cc4[3] = 0.f;
  } else {
#pragma unroll
    for (int rr = 0; rr < 4; ++rr)
      cc4[rr] = cst[(size_t)(b_base + (lg << 2) + rr) * Hh + jmy];
  }
  __syncthreads();

  const f4* xb = (const f4*)xg + ((((size_t)g * 8 + s) * 2 + w) * 4) * 64 + l;
  f4 xgn[4];
#pragma unroll
  for (int q = 0; q < 4; ++q) xgn[q] = xb[q << 6];

  for (int t = 0; t < CH; ++t) {
    // ---- issue all 8 af loads (sc1, MALL-direct); af[kt] = h_{t-1}[b=lrow][kt*32+lg*8..+8)
    const u16* hr = hz + ((size_t)(t0 + t) * Bb + b_base + lrow) * Hh + (lg << 3);
    bf8 af[8];
#pragma unroll
    for (int kt = 0; kt < 8; ++kt) af[kt] = ld_coh16(hr + (kt << 5));

    f4 acc[4];
#pragma unroll
    for (int q = 0; q < 4; ++q) acc[q] = xgn[q];

    // ---- MFMA kt-major; counted waits: only the 8 af loads are outstanding
#pragma unroll
    for (int kt = 0; kt < 8; ++kt) {
      bf8 bfr[4];
#pragma unroll
      for (int q = 0; q < 4; ++q)
        bfr[q] = *(const bf8*)&wlds[(((((q << 1) | w) << 3) | kt) << 9) + (l << 3)];
      asm volatile("s_waitcnt vmcnt(%0)" :: "i"(7 - kt) : "memory");
      __builtin_amdgcn_sched_barrier(0);
#pragma unroll
      for (int q = 0; q < 4; ++q) acc[q] = mfma16(af[kt], bfr[q], acc[q]);
    }

    // ---- prefetch next xg (normal cached loads; drained by the vmcnt(0) below)
    f4 xg2[4];
#pragma unroll
    for (int q = 0; q < 4; ++q) xg2[q] = xb[(size_t)(t + 1) * 32768 + (q << 6)];

    // ---- nonlinearity
    u16 hv[4];
#pragma unroll
    for (int rr = 0; rr < 4; ++rr) {
      float gi = sigm(acc[0][rr]);
      float gf = sigm(acc[1][rr]);
      float gg = tanh_f(acc[2][rr]);
      float go = sigm(acc[3][rr]);
      float c2 = gf * cc4[rr] + gi * gg;
      cc4[rr] = c2;
      hv[rr] = f2bf(go * tanh_f(c2));
    }

    // ---- publish own slice: LDS transpose -> 64 coalesced 16B sc1 stores (wave 0)
#pragma unroll
    for (int rr = 0; rr < 4; ++rr)
      sbuf[(((lg << 2) + rr) << 5) + (w << 4) + lrow] = hv[rr];
    __syncthreads();
    if (tid < 64) {
      int b = tid >> 2, gg = tid & 3;
      bf8 v = *(const bf8*)&sbuf[(b << 5) + (gg << 3)];
      st_coh16(hz + ((size_t)(t0 + t + 1) * Bb + b_base + b) * Hh + (s << 5) + (gg << 3), v);
    }
    asm volatile("s_waitcnt vmcnt(0)" ::: "memory");   // stores acked + xg2 drained
    __syncthreads();

    if (t < CH - 1) {
      int* fl = cnt + (((size_t)(t0 + t) << 3) + g) * 32;   // 128B-padded counter
      if (tid == 0) {
        __builtin_amdgcn_fence(__ATOMIC_RELEASE, "agent");  // cheap: no dirty exchange lines
        (void)__hip_atomic_fetch_add(fl, 1, __ATOMIC_RELAXED, __HIP_MEMORY_SCOPE_AGENT);
      }
      while (__hip_atomic_load(fl, __ATOMIC_RELAXED, __HIP_MEMORY_SCOPE_AGENT) < 8) {}
      __builtin_amdgcn_sched_barrier(0);
    }
#pragma unroll
    for (int q = 0; q < 4; ++q) xgn[q] = xg2[q];
  }

#pragma unroll
  for (int rr = 0; rr < 4; ++rr)
    cst[(size_t)(b_base + (lg << 2) + rr) * Hh + jmy] = cc4[rr];
}

// ---------- final FC ----------
__global__ void k_fc(const u16* __restrict__ h2l, const float* __restrict__ Wfc,
                     const float* __restrict__ bfc, float* __restrict__ out) {
  int b = threadIdx.x;
  if (b < Bb) {
    float s = bfc[0];
    for (int j = 0; j < Hh; ++j) s += bf2f(h2l[(size_t)b * Hh + j]) * Wfc[j];
    out[b] = s;
  }
}

// ---------- driver ----------
extern "C" void kernel_launch(void* const* d_in, const int* in_sizes, int n_in,
                              void* d_out, int out_size, void* d_ws, size_t ws_size,
                              hipStream_t stream) {
  const float* X    = (const float*)d_in[0];
  const float* Wih0 = (const float*)d_in[1];
  const float* Whh0 = (const float*)d_in[2];
  const float* bih0 = (const float*)d_in[3];
  const float* bhh0 = (const float*)d_in[4];
  const float* Wih1 = (const float*)d_in[5];
  const float* Whh1 = (const float*)d_in[6];
  const float* bih1 = (const float*)d_in[7];
  const float* bhh1 = (const float*)d_in[8];
  const float* Wfc  = (const float*)d_in[9];
  const float* bfc  = (const float*)d_in[10];

  char* base = (char*)d_ws;
  size_t off = 0;
  auto alloc = [&](size_t bytes) -> char* {
    char* p = base + off;
    off = (off + bytes + 255) & ~(size_t)255;
    return p;
  };

  u16* Xhi = (u16*)alloc((size_t)Bb * Tt * Dd * 2);
  u16* Xlo = (u16*)alloc((size_t)Bb * Tt * Dd * 2);
  u16* W0h = (u16*)alloc((size_t)G4 * Dd * 2);
  u16* W0l = (u16*)alloc((size_t)G4 * Dd * 2);
  u16* W1h = (u16*)alloc((size_t)G4 * Hh * 2);
  u16* W1l = (u16*)alloc((size_t)G4 * Hh * 2);
  u16* W2a = (u16*)alloc((size_t)G4 * Hh * 2);
  u16* W2b = (u16*)alloc((size_t)G4 * Hh * 2);
  float* b0 = (float*)alloc(G4 * 4);
  float* b1 = (float*)alloc(G4 * 4);
  float* xgb = (float*)alloc((size_t)MCH * G4 * 4);     // 33.5 MB chunk buffer (XGF layout)
  u16* h1Z = (u16*)alloc((size_t)(Tt + 1) * Bb * Hh * 2);   // row 0 = zeros
  u16* h2Z = (u16*)alloc((size_t)(Tt + 1) * Bb * Hh * 2);
  float* cst = (float*)alloc((size_t)Bb * Hh * 4);
  int* cnt = (int*)alloc((size_t)2 * Tt * 8 * 32 * 4);  // 128B-padded [layer][T][8] counters

  k_zero<<<(2 * Tt * 8 * 32 + 255) / 256, 256, 0, stream>>>(cnt, 2 * Tt * 8 * 32);
  k_zrow<<<(Bb * Hh + 255) / 256, 256, 0, stream>>>(h1Z, h2Z);
  k_prep_x<<<(Bb * Tt * Dd) / 256, 256, 0, stream>>>(X, Xhi, Xlo);
  k_split<<<(G4 * Dd) / 256, 256, 0, stream>>>(Wih0, W0h, W0l);
  k_split<<<(G4 * Hh) / 256, 256, 0, stream>>>(Wih1, W1h, W1l);
  k_prep_whh<<<(G4 * Hh) / 256, 256, 0, stream>>>(Whh0, W2a);
  k_prep_whh<<<(G4 * Hh) / 256, 256, 0, stream>>>(Whh1, W2b);
  k_bias<<<4, 256, 0, stream>>>(bih0, bhh0, b0);
  k_bias<<<4, 256, 0, stream>>>(bih1, bhh1, b1);

  for (int c = 0; c < NCH; ++c) {
    k_gemm<Dd, true><<<dim3(64, 8), 256, 0, stream>>>(
        Xhi + (size_t)c * MCH * Dd, Xlo + (size_t)c * MCH * Dd, W0h, W0l, b0, xgb);
    k_recur<<<64, 128, 0, stream>>>(xgb, W2a, h1Z, cst, cnt, c * CH);
  }
  for (int c = 0; c < NCH; ++c) {
    k_gemm<Hh, false><<<dim3(64, 8), 256, 0, stream>>>(
        h1Z + (size_t)(c * CH + 1) * Bb * Hh, nullptr, W1h, W1l, b1, xgb);
    k_recur<<<64, 128, 0, stream>>>(xgb, W2b, h2Z, cst, cnt + Tt * 8 * 32, c * CH);
  }
  k_fc<<<1, 128, 0, stream>>>(h2Z + (size_t)Tt * Bb * Hh, Wfc, bfc, (float*)d_out);

  (void)in_sizes; (void)n_in; (void)out_size; (void)ws_size;
}